// Round 10
// baseline (195.069 us; speedup 1.0000x reference)
//
#include <hip/hip_runtime.h>
#include <hip/hip_bf16.h>

#define BATCH   8192
#define NM      128      // n_models
#define NF      32       // n_feat
#define L1      64
#define L2O     32
#define L3O     16
#define INSZ    512
#define EPSV    1e-5f
#define CH      16       // chunks per model (stats2/final blocks)
#define P64     64       // partial slots, f-major (stats2)
#define GS1B    256      // gs1 blocks, 32 rows each
#define XS_STR  522      // padded LDS stride (ushorts) for x image
#define H1STR   80       // h1 LDS row stride in shorts (160B, 16B-aligned)
#define H2STR   40       // h2 LDS row stride in shorts (80B, 16B-aligned)

typedef __attribute__((ext_vector_type(8))) short short8;
typedef __attribute__((ext_vector_type(4))) float f32x4;

union U8 { short8 s8; unsigned u[4]; };

__device__ inline unsigned short f2bf(float f) {
    union { float f; unsigned u; } v; v.f = f;
    return (unsigned short)((v.u + 0x7FFF + ((v.u >> 16) & 1)) >> 16);
}
__device__ inline unsigned pkbf(float a, float b) {
    union { __hip_bfloat162 h; unsigned u; } c;
    c.h = __float22bfloat162_rn(float2{a, b});
    return c.u;
}

// ---------- k_prep: pack W1/W2/W3 to bf16 fragment order ----------
__global__ __launch_bounds__(256) void k_prep(
    const float* __restrict__ W1, const float* __restrict__ W2,
    const float* __restrict__ W3,
    unsigned short* __restrict__ W1p, unsigned short* __restrict__ W2p,
    unsigned short* __restrict__ W3p)
{
    int g = blockIdx.x*256 + threadIdx.x;      // NM*4608 total
    int m = g / 4608, r = g % 4608;
    if (r < 2048) {
        int n = r >> 9, l = (r >> 3) & 63, s = r & 7;
        W1p[m*2048 + r] = f2bf(W1[m*2048 + ((l>>4)*8+s)*L1 + n*16 + (l&15)]);
    } else if (r < 4096) {
        int q = r - 2048;
        int f = q >> 9, l = (q >> 3) & 63, s = q & 7;
        int n2 = f >> 1, ks = f & 1;
        W2p[m*2048 + q] = f2bf(W2[m*2048 + (ks*32+(l>>4)*8+s)*L2O + n2*16 + (l&15)]);
    } else {
        int q = r - 4096;
        int l = (q >> 3) & 63, s = q & 7;
        W3p[m*512 + q] = f2bf(W3[m*512 + ((l>>4)*8+s)*L3O + (l&15)]);
    }
}

// ---------- k_gs1: stage x -> LDS + write-through x_bf + stats1 partials ----------
// 256 blocks x 512 threads; block = 32 batch rows. NO Ag materialization.
__global__ __launch_bounds__(512) void k_gs1(
    const float* __restrict__ x, const int* __restrict__ uf,
    const unsigned short* __restrict__ W1p,
    unsigned short* __restrict__ xbf,
    float* __restrict__ s1sum, float* __restrict__ s1sq)
{
    __shared__ unsigned short xs[32*XS_STR];   // 33.4 KB
    __shared__ int sUf[NM*NF];                 // 16 KB
    const int blk = blockIdx.x, t = threadIdx.x;
    #pragma unroll
    for (int p = 0; p < 8; ++p) {
        const float4 v = *(const float4*)(x + (size_t)blk*32*INSZ + p*2048 + t*4);
        const int row = 4*p + (t>>7), col = (t&127)*4;
        uint2 pk; pk.x = pkbf(v.x, v.y); pk.y = pkbf(v.z, v.w);
        *(uint2*)(&xs[row*XS_STR + col]) = pk;
        *(uint2*)(xbf + ((size_t)blk*32 + row)*INSZ + col) = pk;   // compact global bf16 image
    }
    #pragma unroll
    for (int p = 0; p < 2; ++p)
        ((int4*)sUf)[t + p*512] = ((const int4*)uf)[t + p*512];
    __syncthreads();

    const int w = t >> 6, l = t & 63, lr = l & 15, lg = l >> 4;
    const unsigned short* xr0 = xs + lr*XS_STR;
    const unsigned short* xr1 = xs + (16+lr)*XS_STR;
    for (int mi = 0; mi < 16; ++mi) {
        const int m = w*16 + mi;
        const int4 ia = ((const int4*)sUf)[m*8 + lg*2];
        const int4 ib = ((const int4*)sUf)[m*8 + lg*2 + 1];
        U8 A0, A1;
        A0.u[0] = xr0[ia.x] | ((unsigned)xr0[ia.y] << 16);
        A0.u[1] = xr0[ia.z] | ((unsigned)xr0[ia.w] << 16);
        A0.u[2] = xr0[ib.x] | ((unsigned)xr0[ib.y] << 16);
        A0.u[3] = xr0[ib.z] | ((unsigned)xr0[ib.w] << 16);
        A1.u[0] = xr1[ia.x] | ((unsigned)xr1[ia.y] << 16);
        A1.u[1] = xr1[ia.z] | ((unsigned)xr1[ia.w] << 16);
        A1.u[2] = xr1[ib.x] | ((unsigned)xr1[ib.y] << 16);
        A1.u[3] = xr1[ib.z] | ((unsigned)xr1[ib.w] << 16);
        float sum[4], sq[4];
        #pragma unroll
        for (int n = 0; n < 4; ++n) {
            const short8 wf = *(const short8*)(W1p + m*2048 + n*512 + l*8);
            f32x4 z = {0.f,0.f,0.f,0.f};
            f32x4 c0 = __builtin_amdgcn_mfma_f32_16x16x32_bf16(A0.s8, wf, z, 0, 0, 0);
            f32x4 c1 = __builtin_amdgcn_mfma_f32_16x16x32_bf16(A1.s8, wf, z, 0, 0, 0);
            sum[n] = (c0[0]+c0[1]) + (c0[2]+c0[3]) + (c1[0]+c1[1]) + (c1[2]+c1[3]);
            sq[n]  = c0[0]*c0[0] + c0[1]*c0[1] + c0[2]*c0[2] + c0[3]*c0[3]
                   + c1[0]*c1[0] + c1[1]*c1[1] + c1[2]*c1[2] + c1[3]*c1[3];
        }
        #pragma unroll
        for (int n = 0; n < 4; ++n) {
            sum[n] += __shfl_xor(sum[n], 16); sum[n] += __shfl_xor(sum[n], 32);
            sq[n]  += __shfl_xor(sq[n], 16);  sq[n]  += __shfl_xor(sq[n], 32);
        }
        if (l < 16) {
            #pragma unroll
            for (int n = 0; n < 4; ++n) {
                s1sum[(size_t)blk*8192 + m*64 + n*16 + l] = sum[n];
                s1sq [(size_t)blk*8192 + m*64 + n*16 + l] = sq[n];
            }
        }
    }
}

// ---------- finalize (both layouts) ----------
__global__ __launch_bounds__(256) void k_fin(
    const float* __restrict__ sump, const float* __restrict__ sqp,
    const float* __restrict__ bias, const float* __restrict__ gamma,
    const float* __restrict__ beta, float* __restrict__ scale,
    float* __restrict__ shift, int nfeat, int parts, int slotMajor)
{
    int f = blockIdx.x*256 + threadIdx.x;
    if (f >= nfeat) return;
    float S = 0.f, Q = 0.f;
    if (slotMajor) {
        #pragma unroll 8
        for (int c = 0; c < parts; ++c) { S += sump[(size_t)c*nfeat + f]; Q += sqp[(size_t)c*nfeat + f]; }
    } else {
        #pragma unroll 8
        for (int c = 0; c < parts; ++c) { S += sump[(size_t)f*parts + c]; Q += sqp[(size_t)f*parts + c]; }
    }
    float mz   = S * (1.f/BATCH);
    float var  = Q * (1.f/BATCH) - mz*mz;     // shift-invariant
    float mean = mz + bias[f];
    float sc   = rsqrtf(var + EPSV) * gamma[f];
    scale[f] = sc; shift[f] = beta[f] - mean*sc;
}

// gather A-fragment for (rbG, m) from the compact bf16 x image (L2/L3-hot)
__device__ __forceinline__ short8 gatherFrag(
    const unsigned short* __restrict__ xbf, int rbG, int lr,
    const int4 ia, const int4 ib)
{
    const unsigned short* xr = xbf + ((size_t)rbG*16 + lr)*INSZ;
    U8 A;
    A.u[0] = xr[ia.x] | ((unsigned)xr[ia.y] << 16);
    A.u[1] = xr[ia.z] | ((unsigned)xr[ia.w] << 16);
    A.u[2] = xr[ib.x] | ((unsigned)xr[ib.y] << 16);
    A.u[3] = xr[ib.z] | ((unsigned)xr[ib.w] << 16);
    return A.s8;
}

// ---------- k_stats2g: gather + dense1(swapped) -> BN1+ReLU -> dense2 stats ----------
__global__ __launch_bounds__(256) void k_stats2g(
    const unsigned short* __restrict__ xbf, const int* __restrict__ uf,
    const unsigned short* __restrict__ W1p,
    const float* __restrict__ scale1, const float* __restrict__ shift1,
    const unsigned short* __restrict__ W2p,
    float* __restrict__ sum2p, float* __restrict__ sq2p)
{
    __shared__ unsigned short h1T[4][16*H1STR];   // 10 KB
    const int m = blockIdx.x >> 4, chunk = blockIdx.x & 15;
    const int t = threadIdx.x, w = t >> 6, l = t & 63;
    const int lr = l & 15, lg = l >> 4;
    const int4 ia = ((const int4*)uf)[m*8 + lg*2];      // loop-invariant indices
    const int4 ib = ((const int4*)uf)[m*8 + lg*2 + 1];
    short8 w1f[4];
    #pragma unroll
    for (int n = 0; n < 4; ++n) w1f[n] = *(const short8*)(W1p + m*2048 + n*512 + l*8);
    short8 w2f[2][2];
    #pragma unroll
    for (int n2 = 0; n2 < 2; ++n2)
        #pragma unroll
        for (int ks = 0; ks < 2; ++ks)
            w2f[n2][ks] = *(const short8*)(W2p + m*2048 + (n2*2+ks)*512 + l*8);
    float4 sc1q[4], sh1q[4];
    #pragma unroll
    for (int n = 0; n < 4; ++n) {
        sc1q[n] = *(const float4*)(scale1 + m*L1 + n*16 + lg*4);
        sh1q[n] = *(const float4*)(shift1 + m*L1 + n*16 + lg*4);
    }
    unsigned short* hT = &h1T[w][0];
    float sumf[8] = {0,0,0,0,0,0,0,0}, sqf[8] = {0,0,0,0,0,0,0,0};
    for (int i = 0; i < 8; ++i) {
        const int rbG = chunk*32 + i*4 + w;
        const short8 a = gatherFrag(xbf, rbG, lr, ia, ib);
        #pragma unroll
        for (int n = 0; n < 4; ++n) {
            f32x4 z = {0.f,0.f,0.f,0.f};
            // swapped: lane holds z1^T rows = feats n*16+lg*4+r, col = batch lr
            f32x4 acc = __builtin_amdgcn_mfma_f32_16x16x32_bf16(w1f[n], a, z, 0, 0, 0);
            float h0 = acc[0]*sc1q[n].x + sh1q[n].x; h0 = h0 > 0.f ? h0 : 0.f;
            float h1 = acc[1]*sc1q[n].y + sh1q[n].y; h1 = h1 > 0.f ? h1 : 0.f;
            float h2 = acc[2]*sc1q[n].z + sh1q[n].z; h2 = h2 > 0.f ? h2 : 0.f;
            float h3 = acc[3]*sc1q[n].w + sh1q[n].w; h3 = h3 > 0.f ? h3 : 0.f;
            uint2 pk; pk.x = pkbf(h0, h1); pk.y = pkbf(h2, h3);
            *(uint2*)(hT + lr*H1STR + n*16 + lg*4) = pk;
        }
        const short8 a20 = *(const short8*)(hT + lr*H1STR + lg*8);
        const short8 a21 = *(const short8*)(hT + lr*H1STR + 32 + lg*8);
        #pragma unroll
        for (int n2 = 0; n2 < 2; ++n2) {
            f32x4 z = {0.f,0.f,0.f,0.f};
            f32x4 acc = __builtin_amdgcn_mfma_f32_16x16x32_bf16(w2f[n2][0], a20, z, 0, 0, 0);
            acc = __builtin_amdgcn_mfma_f32_16x16x32_bf16(w2f[n2][1], a21, acc, 0, 0, 0);
            #pragma unroll
            for (int r = 0; r < 4; ++r) {
                sumf[n2*4+r] += acc[r];
                sqf [n2*4+r] += acc[r]*acc[r];
            }
        }
    }
    #pragma unroll
    for (int j = 0; j < 8; ++j) {
        #pragma unroll
        for (int mk = 1; mk < 16; mk <<= 1) {
            sumf[j] += __shfl_xor(sumf[j], mk);
            sqf[j]  += __shfl_xor(sqf[j], mk);
        }
    }
    if (lr == 0) {
        const int slot = chunk*4 + w;
        #pragma unroll
        for (int n2 = 0; n2 < 2; ++n2)
            #pragma unroll
            for (int r = 0; r < 4; ++r) {
                const int f = m*L2O + n2*16 + lg*4 + r;
                sum2p[(size_t)f*P64 + slot] = sumf[n2*4+r];
                sq2p [(size_t)f*P64 + slot] = sqf[n2*4+r];
            }
    }
}

// ---------- k_finalg: gather + full recompute -> pred + outpartT ----------
__global__ __launch_bounds__(256) void k_finalg(
    const unsigned short* __restrict__ xbf, const int* __restrict__ uf,
    const unsigned short* __restrict__ W1p,
    const float* __restrict__ scale1, const float* __restrict__ shift1,
    const unsigned short* __restrict__ W2p,
    const float* __restrict__ scale2, const float* __restrict__ shift2,
    const unsigned short* __restrict__ W3p, const float* __restrict__ b3,
    const float* __restrict__ ow,
    float* __restrict__ pred, float* __restrict__ outpartT)
{
    __shared__ unsigned short h1T[4][16*H1STR];   // 10 KB
    __shared__ unsigned short h2T[4][16*H2STR];   // 5 KB
    const int m = blockIdx.x >> 4, chunk = blockIdx.x & 15;
    const int t = threadIdx.x, w = t >> 6, l = t & 63;
    const int lr = l & 15, lg = l >> 4;
    const int4 ia = ((const int4*)uf)[m*8 + lg*2];
    const int4 ib = ((const int4*)uf)[m*8 + lg*2 + 1];
    short8 w1f[4];
    #pragma unroll
    for (int n = 0; n < 4; ++n) w1f[n] = *(const short8*)(W1p + m*2048 + n*512 + l*8);
    short8 w2f[2][2];
    #pragma unroll
    for (int n2 = 0; n2 < 2; ++n2)
        #pragma unroll
        for (int ks = 0; ks < 2; ++ks)
            w2f[n2][ks] = *(const short8*)(W2p + m*2048 + (n2*2+ks)*512 + l*8);
    const short8 w3f = *(const short8*)(W3p + m*512 + l*8);
    float4 sc1q[4], sh1q[4];
    #pragma unroll
    for (int n = 0; n < 4; ++n) {
        sc1q[n] = *(const float4*)(scale1 + m*L1 + n*16 + lg*4);
        sh1q[n] = *(const float4*)(shift1 + m*L1 + n*16 + lg*4);
    }
    float4 sc2q[2], sh2q[2];
    #pragma unroll
    for (int n2 = 0; n2 < 2; ++n2) {
        sc2q[n2] = *(const float4*)(scale2 + m*L2O + n2*16 + lg*4);
        sh2q[n2] = *(const float4*)(shift2 + m*L2O + n2*16 + lg*4);
    }
    const float4 b3f = *(const float4*)(b3 + m*L3O + lg*4);
    const float4 owf = *(const float4*)(ow + m*L3O + lg*4);
    f32x4 cb3; cb3[0] = b3f.x; cb3[1] = b3f.y; cb3[2] = b3f.z; cb3[3] = b3f.w;
    unsigned short* hT  = &h1T[w][0];
    unsigned short* hT2 = &h2T[w][0];
    for (int i = 0; i < 8; ++i) {
        const int rbG = chunk*32 + i*4 + w;
        const short8 a = gatherFrag(xbf, rbG, lr, ia, ib);
        #pragma unroll
        for (int n = 0; n < 4; ++n) {
            f32x4 z = {0.f,0.f,0.f,0.f};
            f32x4 acc = __builtin_amdgcn_mfma_f32_16x16x32_bf16(w1f[n], a, z, 0, 0, 0);
            float h0 = acc[0]*sc1q[n].x + sh1q[n].x; h0 = h0 > 0.f ? h0 : 0.f;
            float h1 = acc[1]*sc1q[n].y + sh1q[n].y; h1 = h1 > 0.f ? h1 : 0.f;
            float h2 = acc[2]*sc1q[n].z + sh1q[n].z; h2 = h2 > 0.f ? h2 : 0.f;
            float h3 = acc[3]*sc1q[n].w + sh1q[n].w; h3 = h3 > 0.f ? h3 : 0.f;
            uint2 pk; pk.x = pkbf(h0, h1); pk.y = pkbf(h2, h3);
            *(uint2*)(hT + lr*H1STR + n*16 + lg*4) = pk;
        }
        const short8 a20 = *(const short8*)(hT + lr*H1STR + lg*8);
        const short8 a21 = *(const short8*)(hT + lr*H1STR + 32 + lg*8);
        #pragma unroll
        for (int n2 = 0; n2 < 2; ++n2) {
            f32x4 z = {0.f,0.f,0.f,0.f};
            f32x4 acc = __builtin_amdgcn_mfma_f32_16x16x32_bf16(w2f[n2][0], a20, z, 0, 0, 0);
            acc = __builtin_amdgcn_mfma_f32_16x16x32_bf16(w2f[n2][1], a21, acc, 0, 0, 0);
            float h0 = acc[0]*sc2q[n2].x + sh2q[n2].x; h0 = h0 > 0.f ? h0 : 0.f;
            float h1 = acc[1]*sc2q[n2].y + sh2q[n2].y; h1 = h1 > 0.f ? h1 : 0.f;
            float h2 = acc[2]*sc2q[n2].z + sh2q[n2].z; h2 = h2 > 0.f ? h2 : 0.f;
            float h3 = acc[3]*sc2q[n2].w + sh2q[n2].w; h3 = h3 > 0.f ? h3 : 0.f;
            uint2 pk; pk.x = pkbf(h0, h1); pk.y = pkbf(h2, h3);
            *(uint2*)(hT2 + lr*H2STR + n2*16 + lg*4) = pk;
        }
        {
            const short8 a3 = *(const short8*)(hT2 + lr*H2STR + lg*8);
            // b3 folded into MFMA C operand (C layout == D layout)
            f32x4 acc = __builtin_amdgcn_mfma_f32_16x16x32_bf16(w3f, a3, cb3, 0, 0, 0);
            float4 pv;
            pv.x = acc[0]; pv.y = acc[1]; pv.z = acc[2]; pv.w = acc[3];
            const size_t row = (size_t)rbG*16 + lr;
            *(float4*)(pred + row*(NM*L3O) + m*L3O + lg*4) = pv;
            float v = pv.x*owf.x + pv.y*owf.y + pv.z*owf.z + pv.w*owf.w;
            v += __shfl_xor(v, 16); v += __shfl_xor(v, 32);
            if (l < 16) outpartT[(size_t)m*BATCH + rbG*16 + l] = v;
        }
    }
}

// ---------- k_outT ----------
__global__ __launch_bounds__(256) void k_outT(
    const float* __restrict__ outpartT, const float* __restrict__ ob,
    float* __restrict__ out)
{
    int b = blockIdx.x*256 + threadIdx.x;
    float acc = ob[0];
    #pragma unroll 8
    for (int m = 0; m < NM; ++m) acc += outpartT[(size_t)m*BATCH + b];
    out[b] = acc;
}

extern "C" void kernel_launch(void* const* d_in, const int* in_sizes, int n_in,
                              void* d_out, int out_size, void* d_ws, size_t ws_size,
                              hipStream_t stream) {
    const float* x   = (const float*)d_in[0];
    const int*   uf  = (const int*  )d_in[1];
    const float* W1  = (const float*)d_in[2];
    const float* b1  = (const float*)d_in[3];
    const float* W2  = (const float*)d_in[4];
    const float* b2  = (const float*)d_in[5];
    const float* W3  = (const float*)d_in[6];
    const float* b3  = (const float*)d_in[7];
    const float* g1  = (const float*)d_in[8];
    const float* be1 = (const float*)d_in[9];
    const float* g2  = (const float*)d_in[10];
    const float* be2 = (const float*)d_in[11];
    const float* ow  = (const float*)d_in[12];
    const float* ob  = (const float*)d_in[13];

    float* out  = (float*)d_out;
    float* pred = out + BATCH;

    // workspace (~35 MB total; ws proven >= 103 MB)
    unsigned short* W1p = (unsigned short*)d_ws;            // NM*2048
    unsigned short* W2p = W1p + NM*2048;
    unsigned short* W3p = W2p + NM*2048;
    unsigned short* xbf = W3p + NM*512;                     // [8192][512] bf16 = 8.4 MB
    float* scale1 = (float*)(xbf + (size_t)BATCH*INSZ);
    float* shift1 = scale1 + NM*L1;
    float* scale2 = shift1 + NM*L1;
    float* shift2 = scale2 + NM*L2O;
    float* s1sum  = shift2 + NM*L2O;                        // [256][8192] slot-major
    float* s1sq   = s1sum + (size_t)GS1B*8192;
    float* s2sum  = s1sq  + (size_t)GS1B*8192;              // [f][64] f-major
    float* s2sq   = s2sum + (size_t)NM*L2O*P64;
    float* outpartT = s2sq + (size_t)NM*L2O*P64;            // [NM][BATCH] = 4.2 MB

    k_prep<<<NM*4608/256, 256, 0, stream>>>(W1, W2, W3, W1p, W2p, W3p);
    k_gs1<<<GS1B, 512, 0, stream>>>(x, uf, W1p, xbf, s1sum, s1sq);
    k_fin<<<NM*L1/256, 256, 0, stream>>>(s1sum, s1sq, b1, g1, be1, scale1, shift1, NM*L1, GS1B, 1);
    k_stats2g<<<NM*CH, 256, 0, stream>>>(xbf, uf, W1p, scale1, shift1, W2p, s2sum, s2sq);
    k_fin<<<NM*L2O/256, 256, 0, stream>>>(s2sum, s2sq, b2, g2, be2, scale2, shift2, NM*L2O, P64, 0);
    k_finalg<<<NM*CH, 256, 0, stream>>>(xbf, uf, W1p, scale1, shift1, W2p, scale2, shift2,
                                        W3p, b3, ow, pred, outpartT);
    k_outT<<<BATCH/256, 256, 0, stream>>>(outpartT, ob, out);
}

// Round 11
// 114.373 us; speedup vs baseline: 1.7056x; 1.7056x over previous
//
#include <hip/hip_runtime.h>
#include <hip/hip_bf16.h>

#define BATCH   8192
#define NM      128      // n_models
#define NF      32       // n_feat
#define L1      64
#define L2O     32
#define L3O     16
#define INSZ    512
#define EPSV    1e-5f
#define CH      16       // chunks per model (stats2/final blocks)
#define P64     64       // partial slots, f-major layout (stats2 + path B)
#define GS1B    256      // k_gs1 blocks (path A), 32 rows each
#define XS_STR  522      // padded LDS stride (ushorts) for x image
#define H1STR   72       // h1 LDS row stride in shorts (144B: 16B-aligned, 2-way banks)
#define H2STR   40       // h2 LDS row stride in shorts (80B: 16B-aligned, 2-way banks)

typedef __attribute__((ext_vector_type(8))) short short8;
typedef __attribute__((ext_vector_type(4))) float f32x4;

union U8 { short8 s8; unsigned u[4]; };

__device__ inline unsigned short f2bf(float f) {
    union { float f; unsigned u; } v; v.f = f;
    return (unsigned short)((v.u + 0x7FFF + ((v.u >> 16) & 1)) >> 16);
}
__device__ inline unsigned pkbf(float a, float b) {
    union { __hip_bfloat162 h; unsigned u; } c;
    c.h = __float22bfloat162_rn(float2{a, b});
    return c.u;
}

// ---------- k_prep: pack W1/W2/W3 to bf16 fragment order ----------
__global__ __launch_bounds__(256) void k_prep(
    const float* __restrict__ W1, const float* __restrict__ W2,
    const float* __restrict__ W3,
    unsigned short* __restrict__ W1p, unsigned short* __restrict__ W2p,
    unsigned short* __restrict__ W3p)
{
    int g = blockIdx.x*256 + threadIdx.x;      // NM*4608 total
    int m = g / 4608, r = g % 4608;
    if (r < 2048) {
        int n = r >> 9, l = (r >> 3) & 63, s = r & 7;
        W1p[m*2048 + r] = f2bf(W1[m*2048 + ((l>>4)*8+s)*L1 + n*16 + (l&15)]);
    } else if (r < 4096) {
        int q = r - 2048;
        int f = q >> 9, l = (q >> 3) & 63, s = q & 7;
        int n2 = f >> 1, ks = f & 1;
        W2p[m*2048 + q] = f2bf(W2[m*2048 + (ks*32+(l>>4)*8+s)*L2O + n2*16 + (l&15)]);
    } else {
        int q = r - 4096;
        int l = (q >> 3) & 63, s = q & 7;
        W3p[m*512 + q] = f2bf(W3[m*512 + ((l>>4)*8+s)*L3O + (l&15)]);
    }
}

// ---------- k_gs1 (path A): fused gather + Ag write + stats1 partials ----------
__global__ __launch_bounds__(512) void k_gs1(
    const float* __restrict__ x, const int* __restrict__ uf,
    const unsigned short* __restrict__ W1p,
    unsigned short* __restrict__ Ag,
    float* __restrict__ s1sum, float* __restrict__ s1sq)
{
    __shared__ unsigned short xs[32*XS_STR];   // 33.4 KB
    __shared__ int sUf[NM*NF];                 // 16 KB
    const int blk = blockIdx.x, t = threadIdx.x;
    #pragma unroll
    for (int p = 0; p < 8; ++p) {
        const float4 v = *(const float4*)(x + (size_t)blk*32*INSZ + p*2048 + t*4);
        const int row = 4*p + (t>>7), col = (t&127)*4;
        *(unsigned*)(&xs[row*XS_STR + col])     = pkbf(v.x, v.y);
        *(unsigned*)(&xs[row*XS_STR + col + 2]) = pkbf(v.z, v.w);
    }
    #pragma unroll
    for (int p = 0; p < 2; ++p)
        ((int4*)sUf)[t + p*512] = ((const int4*)uf)[t + p*512];
    __syncthreads();

    const int w = t >> 6, l = t & 63, lr = l & 15, lg = l >> 4;
    const unsigned short* xr0 = xs + lr*XS_STR;
    const unsigned short* xr1 = xs + (16+lr)*XS_STR;
    for (int mi = 0; mi < 16; ++mi) {
        const int m = w*16 + mi;
        const int4 ia = ((const int4*)sUf)[m*8 + lg*2];
        const int4 ib = ((const int4*)sUf)[m*8 + lg*2 + 1];
        U8 A0, A1;
        A0.u[0] = xr0[ia.x] | ((unsigned)xr0[ia.y] << 16);
        A0.u[1] = xr0[ia.z] | ((unsigned)xr0[ia.w] << 16);
        A0.u[2] = xr0[ib.x] | ((unsigned)xr0[ib.y] << 16);
        A0.u[3] = xr0[ib.z] | ((unsigned)xr0[ib.w] << 16);
        A1.u[0] = xr1[ia.x] | ((unsigned)xr1[ia.y] << 16);
        A1.u[1] = xr1[ia.z] | ((unsigned)xr1[ia.w] << 16);
        A1.u[2] = xr1[ib.x] | ((unsigned)xr1[ib.y] << 16);
        A1.u[3] = xr1[ib.z] | ((unsigned)xr1[ib.w] << 16);
        *(short8*)(Ag + ((size_t)(blk*2  )*NM + m)*512 + lr*32 + lg*8) = A0.s8;
        *(short8*)(Ag + ((size_t)(blk*2+1)*NM + m)*512 + lr*32 + lg*8) = A1.s8;
        float sum[4], sq[4];
        #pragma unroll
        for (int n = 0; n < 4; ++n) {
            const short8 wf = *(const short8*)(W1p + m*2048 + n*512 + l*8);
            f32x4 z = {0.f,0.f,0.f,0.f};
            f32x4 c0 = __builtin_amdgcn_mfma_f32_16x16x32_bf16(A0.s8, wf, z, 0, 0, 0);
            f32x4 c1 = __builtin_amdgcn_mfma_f32_16x16x32_bf16(A1.s8, wf, z, 0, 0, 0);
            sum[n] = (c0[0]+c0[1]) + (c0[2]+c0[3]) + (c1[0]+c1[1]) + (c1[2]+c1[3]);
            sq[n]  = c0[0]*c0[0] + c0[1]*c0[1] + c0[2]*c0[2] + c0[3]*c0[3]
                   + c1[0]*c1[0] + c1[1]*c1[1] + c1[2]*c1[2] + c1[3]*c1[3];
        }
        #pragma unroll
        for (int n = 0; n < 4; ++n) {
            sum[n] += __shfl_xor(sum[n], 16); sum[n] += __shfl_xor(sum[n], 32);
            sq[n]  += __shfl_xor(sq[n], 16);  sq[n]  += __shfl_xor(sq[n], 32);
        }
        if (l < 16) {
            #pragma unroll
            for (int n = 0; n < 4; ++n) {
                s1sum[(size_t)blk*8192 + m*64 + n*16 + l] = sum[n];
                s1sq [(size_t)blk*8192 + m*64 + n*16 + l] = sq[n];
            }
        }
    }
}

// ---------- finalize (both layouts) ----------
__global__ __launch_bounds__(256) void k_fin(
    const float* __restrict__ sump, const float* __restrict__ sqp,
    const float* __restrict__ bias, const float* __restrict__ gamma,
    const float* __restrict__ beta, float* __restrict__ scale,
    float* __restrict__ shift, int nfeat, int parts, int slotMajor)
{
    int f = blockIdx.x*256 + threadIdx.x;
    if (f >= nfeat) return;
    float S = 0.f, Q = 0.f;
    if (slotMajor) {
        #pragma unroll 8
        for (int c = 0; c < parts; ++c) { S += sump[(size_t)c*nfeat + f]; Q += sqp[(size_t)c*nfeat + f]; }
    } else {
        #pragma unroll 8
        for (int c = 0; c < parts; ++c) { S += sump[(size_t)f*parts + c]; Q += sqp[(size_t)f*parts + c]; }
    }
    float mz   = S * (1.f/BATCH);
    float var  = Q * (1.f/BATCH) - mz*mz;     // shift-invariant
    float mean = mz + bias[f];
    float sc   = rsqrtf(var + EPSV) * gamma[f];
    scale[f] = sc; shift[f] = beta[f] - mean*sc;
}

// ---------- k_stats2_p: swapped-operand recompute z1 -> BN1+ReLU -> dense2 stats ----------
__global__ __launch_bounds__(256) void k_stats2_p(
    const unsigned short* __restrict__ Ag, const unsigned short* __restrict__ W1p,
    const float* __restrict__ scale1, const float* __restrict__ shift1,
    const unsigned short* __restrict__ W2p,
    float* __restrict__ sum2p, float* __restrict__ sq2p)
{
    __shared__ unsigned short h1T[4][16*H1STR];   // 9 KB
    const int m = blockIdx.x >> 4, chunk = blockIdx.x & 15;
    const int t = threadIdx.x, w = t >> 6, l = t & 63;
    const int lr = l & 15, lg = l >> 4;
    short8 w1f[4];
    #pragma unroll
    for (int n = 0; n < 4; ++n) w1f[n] = *(const short8*)(W1p + m*2048 + n*512 + l*8);
    short8 w2f[2][2];
    #pragma unroll
    for (int n2 = 0; n2 < 2; ++n2)
        #pragma unroll
        for (int ks = 0; ks < 2; ++ks)
            w2f[n2][ks] = *(const short8*)(W2p + m*2048 + (n2*2+ks)*512 + l*8);
    float4 sc1q[4], sh1q[4];
    #pragma unroll
    for (int n = 0; n < 4; ++n) {
        sc1q[n] = *(const float4*)(scale1 + m*L1 + n*16 + lg*4);
        sh1q[n] = *(const float4*)(shift1 + m*L1 + n*16 + lg*4);
    }
    unsigned short* hT = &h1T[w][0];
    float sumf[8] = {0,0,0,0,0,0,0,0}, sqf[8] = {0,0,0,0,0,0,0,0};
    for (int i = 0; i < 8; ++i) {
        const int rbG = chunk*32 + i*4 + w;
        const short8 a = *(const short8*)(Ag + ((size_t)rbG*NM + m)*512 + lr*32 + lg*8);
        #pragma unroll
        for (int n = 0; n < 4; ++n) {
            f32x4 z = {0.f,0.f,0.f,0.f};
            // swapped: lane holds z1^T rows = feats n*16+lg*4+r, col = batch lr
            f32x4 acc = __builtin_amdgcn_mfma_f32_16x16x32_bf16(w1f[n], a, z, 0, 0, 0);
            float h0 = acc[0]*sc1q[n].x + sh1q[n].x; h0 = h0 > 0.f ? h0 : 0.f;
            float h1 = acc[1]*sc1q[n].y + sh1q[n].y; h1 = h1 > 0.f ? h1 : 0.f;
            float h2 = acc[2]*sc1q[n].z + sh1q[n].z; h2 = h2 > 0.f ? h2 : 0.f;
            float h3 = acc[3]*sc1q[n].w + sh1q[n].w; h3 = h3 > 0.f ? h3 : 0.f;
            uint2 pk; pk.x = pkbf(h0, h1); pk.y = pkbf(h2, h3);
            *(uint2*)(hT + lr*H1STR + n*16 + lg*4) = pk;
        }
        const short8 a20 = *(const short8*)(hT + lr*H1STR + lg*8);
        const short8 a21 = *(const short8*)(hT + lr*H1STR + 32 + lg*8);
        #pragma unroll
        for (int n2 = 0; n2 < 2; ++n2) {
            f32x4 z = {0.f,0.f,0.f,0.f};
            f32x4 acc = __builtin_amdgcn_mfma_f32_16x16x32_bf16(w2f[n2][0], a20, z, 0, 0, 0);
            acc = __builtin_amdgcn_mfma_f32_16x16x32_bf16(w2f[n2][1], a21, acc, 0, 0, 0);
            #pragma unroll
            for (int r = 0; r < 4; ++r) {
                sumf[n2*4+r] += acc[r];
                sqf [n2*4+r] += acc[r]*acc[r];
            }
        }
    }
    #pragma unroll
    for (int j = 0; j < 8; ++j) {
        #pragma unroll
        for (int mk = 1; mk < 16; mk <<= 1) {
            sumf[j] += __shfl_xor(sumf[j], mk);
            sqf[j]  += __shfl_xor(sqf[j], mk);
        }
    }
    if (lr == 0) {
        const int slot = chunk*4 + w;
        #pragma unroll
        for (int n2 = 0; n2 < 2; ++n2)
            #pragma unroll
            for (int r = 0; r < 4; ++r) {
                const int f = m*L2O + n2*16 + lg*4 + r;
                sum2p[(size_t)f*P64 + slot] = sumf[n2*4+r];
                sq2p [(size_t)f*P64 + slot] = sqf[n2*4+r];
            }
    }
}

// ---------- k_final_p: swapped-operand full recompute -> pred + outpartT ----------
__global__ __launch_bounds__(256) void k_final_p(
    const unsigned short* __restrict__ Ag, const unsigned short* __restrict__ W1p,
    const float* __restrict__ scale1, const float* __restrict__ shift1,
    const unsigned short* __restrict__ W2p,
    const float* __restrict__ scale2, const float* __restrict__ shift2,
    const unsigned short* __restrict__ W3p, const float* __restrict__ b3,
    const float* __restrict__ ow,
    float* __restrict__ pred, float* __restrict__ outpartT)
{
    __shared__ unsigned short h1T[4][16*H1STR];   // 9 KB
    __shared__ unsigned short h2T[4][16*H2STR];   // 5 KB
    const int m = blockIdx.x >> 4, chunk = blockIdx.x & 15;
    const int t = threadIdx.x, w = t >> 6, l = t & 63;
    const int lr = l & 15, lg = l >> 4;
    short8 w1f[4];
    #pragma unroll
    for (int n = 0; n < 4; ++n) w1f[n] = *(const short8*)(W1p + m*2048 + n*512 + l*8);
    short8 w2f[2][2];
    #pragma unroll
    for (int n2 = 0; n2 < 2; ++n2)
        #pragma unroll
        for (int ks = 0; ks < 2; ++ks)
            w2f[n2][ks] = *(const short8*)(W2p + m*2048 + (n2*2+ks)*512 + l*8);
    const short8 w3f = *(const short8*)(W3p + m*512 + l*8);
    float4 sc1q[4], sh1q[4];
    #pragma unroll
    for (int n = 0; n < 4; ++n) {
        sc1q[n] = *(const float4*)(scale1 + m*L1 + n*16 + lg*4);
        sh1q[n] = *(const float4*)(shift1 + m*L1 + n*16 + lg*4);
    }
    float4 sc2q[2], sh2q[2];
    #pragma unroll
    for (int n2 = 0; n2 < 2; ++n2) {
        sc2q[n2] = *(const float4*)(scale2 + m*L2O + n2*16 + lg*4);
        sh2q[n2] = *(const float4*)(shift2 + m*L2O + n2*16 + lg*4);
    }
    const float4 b3f = *(const float4*)(b3 + m*L3O + lg*4);
    const float4 owf = *(const float4*)(ow + m*L3O + lg*4);
    f32x4 cb3; cb3[0] = b3f.x; cb3[1] = b3f.y; cb3[2] = b3f.z; cb3[3] = b3f.w;
    unsigned short* hT  = &h1T[w][0];
    unsigned short* hT2 = &h2T[w][0];
    for (int i = 0; i < 8; ++i) {
        const int rbG = chunk*32 + i*4 + w;
        const short8 a = *(const short8*)(Ag + ((size_t)rbG*NM + m)*512 + lr*32 + lg*8);
        #pragma unroll
        for (int n = 0; n < 4; ++n) {
            f32x4 z = {0.f,0.f,0.f,0.f};
            f32x4 acc = __builtin_amdgcn_mfma_f32_16x16x32_bf16(w1f[n], a, z, 0, 0, 0);
            float h0 = acc[0]*sc1q[n].x + sh1q[n].x; h0 = h0 > 0.f ? h0 : 0.f;
            float h1 = acc[1]*sc1q[n].y + sh1q[n].y; h1 = h1 > 0.f ? h1 : 0.f;
            float h2 = acc[2]*sc1q[n].z + sh1q[n].z; h2 = h2 > 0.f ? h2 : 0.f;
            float h3 = acc[3]*sc1q[n].w + sh1q[n].w; h3 = h3 > 0.f ? h3 : 0.f;
            uint2 pk; pk.x = pkbf(h0, h1); pk.y = pkbf(h2, h3);
            *(uint2*)(hT + lr*H1STR + n*16 + lg*4) = pk;
        }
        const short8 a20 = *(const short8*)(hT + lr*H1STR + lg*8);
        const short8 a21 = *(const short8*)(hT + lr*H1STR + 32 + lg*8);
        #pragma unroll
        for (int n2 = 0; n2 < 2; ++n2) {
            f32x4 z = {0.f,0.f,0.f,0.f};
            f32x4 acc = __builtin_amdgcn_mfma_f32_16x16x32_bf16(w2f[n2][0], a20, z, 0, 0, 0);
            acc = __builtin_amdgcn_mfma_f32_16x16x32_bf16(w2f[n2][1], a21, acc, 0, 0, 0);
            float h0 = acc[0]*sc2q[n2].x + sh2q[n2].x; h0 = h0 > 0.f ? h0 : 0.f;
            float h1 = acc[1]*sc2q[n2].y + sh2q[n2].y; h1 = h1 > 0.f ? h1 : 0.f;
            float h2 = acc[2]*sc2q[n2].z + sh2q[n2].z; h2 = h2 > 0.f ? h2 : 0.f;
            float h3 = acc[3]*sc2q[n2].w + sh2q[n2].w; h3 = h3 > 0.f ? h3 : 0.f;
            uint2 pk; pk.x = pkbf(h0, h1); pk.y = pkbf(h2, h3);
            *(uint2*)(hT2 + lr*H2STR + n2*16 + lg*4) = pk;
        }
        {
            const short8 a3 = *(const short8*)(hT2 + lr*H2STR + lg*8);
            // b3 folded into MFMA C operand (C layout == D layout, HW-verified r9/r10)
            f32x4 acc = __builtin_amdgcn_mfma_f32_16x16x32_bf16(w3f, a3, cb3, 0, 0, 0);
            float4 pv;
            pv.x = acc[0]; pv.y = acc[1]; pv.z = acc[2]; pv.w = acc[3];
            const size_t row = (size_t)rbG*16 + lr;
            *(float4*)(pred + row*(NM*L3O) + m*L3O + lg*4) = pv;
            float v = pv.x*owf.x + pv.y*owf.y + pv.z*owf.z + pv.w*owf.w;
            v += __shfl_xor(v, 16); v += __shfl_xor(v, 32);
            if (l < 16) outpartT[(size_t)m*BATCH + rbG*16 + l] = v;
        }
    }
}

// ---------- k_outT ----------
__global__ __launch_bounds__(256) void k_outT(
    const float* __restrict__ outpartT, const float* __restrict__ ob,
    float* __restrict__ out)
{
    int b = blockIdx.x*256 + threadIdx.x;
    float acc = ob[0];
    #pragma unroll 8
    for (int m = 0; m < NM; ++m) acc += outpartT[(size_t)m*BATCH + b];
    out[b] = acc;
}

// ---------- Path B fallback: separate gather + stats1 ----------
__global__ __launch_bounds__(256) void k_gather(
    const float* __restrict__ x, const int* __restrict__ uf,
    unsigned short* __restrict__ Ag)
{
    __shared__ float xs[16*INSZ];
    __shared__ int   sUf[NM*NF];
    const int rb = blockIdx.x;
    const int t  = threadIdx.x;
    const float4* xsrc = (const float4*)(x + (size_t)rb*16*INSZ);
    float4* xdst = (float4*)xs;
    #pragma unroll
    for (int p = 0; p < 8; ++p) xdst[t + p*256] = xsrc[t + p*256];
    const int4* us = (const int4*)uf;
    int4* ud = (int4*)sUf;
    #pragma unroll
    for (int p = 0; p < 4; ++p) ud[t + p*256] = us[t + p*256];
    __syncthreads();
    unsigned* outp = (unsigned*)(Ag + (size_t)rb*NM*512);
    const int e = t*2, r = e >> 5, j = e & 31;
    for (int m = 0; m < NM; ++m) {
        const int i0 = sUf[m*NF + j], i1 = sUf[m*NF + j + 1];
        outp[m*256 + t] = pkbf(xs[r*INSZ + i0], xs[r*INSZ + i1]);
    }
}

__global__ __launch_bounds__(256) void k_stats1_m(
    const unsigned short* __restrict__ Ag, const unsigned short* __restrict__ W1p,
    float* __restrict__ sum1p, float* __restrict__ sq1p)
{
    const int m = blockIdx.x >> 4, chunk = blockIdx.x & 15;
    const int t = threadIdx.x, w = t >> 6, l = t & 63;
    const int lr = l & 15, lg = l >> 4;
    short8 w1f[4];
    #pragma unroll
    for (int n = 0; n < 4; ++n) w1f[n] = *(const short8*)(W1p + m*2048 + n*512 + l*8);
    float sum[4] = {0,0,0,0}, sq[4] = {0,0,0,0};
    for (int i = 0; i < 8; ++i) {
        const int rbG = chunk*32 + i*4 + w;
        const short8 a = *(const short8*)(Ag + ((size_t)rbG*NM + m)*512 + lr*32 + lg*8);
        #pragma unroll
        for (int n = 0; n < 4; ++n) {
            f32x4 acc = {0.f,0.f,0.f,0.f};
            acc = __builtin_amdgcn_mfma_f32_16x16x32_bf16(a, w1f[n], acc, 0, 0, 0);
            sum[n] += (acc[0]+acc[1]) + (acc[2]+acc[3]);
            sq[n]  += acc[0]*acc[0] + acc[1]*acc[1] + acc[2]*acc[2] + acc[3]*acc[3];
        }
    }
    #pragma unroll
    for (int n = 0; n < 4; ++n) {
        sum[n] += __shfl_xor(sum[n], 16); sum[n] += __shfl_xor(sum[n], 32);
        sq[n]  += __shfl_xor(sq[n], 16);  sq[n]  += __shfl_xor(sq[n], 32);
    }
    if (l < 16) {
        const int slot = chunk*4 + w;
        #pragma unroll
        for (int n = 0; n < 4; ++n) {
            const int f = m*L1 + n*16 + l;
            sum1p[(size_t)f*P64 + slot] = sum[n];
            sq1p [(size_t)f*P64 + slot] = sq[n];
        }
    }
}

extern "C" void kernel_launch(void* const* d_in, const int* in_sizes, int n_in,
                              void* d_out, int out_size, void* d_ws, size_t ws_size,
                              hipStream_t stream) {
    const float* x   = (const float*)d_in[0];
    const int*   uf  = (const int*  )d_in[1];
    const float* W1  = (const float*)d_in[2];
    const float* b1  = (const float*)d_in[3];
    const float* W2  = (const float*)d_in[4];
    const float* b2  = (const float*)d_in[5];
    const float* W3  = (const float*)d_in[6];
    const float* b3  = (const float*)d_in[7];
    const float* g1  = (const float*)d_in[8];
    const float* be1 = (const float*)d_in[9];
    const float* g2  = (const float*)d_in[10];
    const float* be2 = (const float*)d_in[11];
    const float* ow  = (const float*)d_in[12];
    const float* ob  = (const float*)d_in[13];

    float* out  = (float*)d_out;
    float* pred = out + BATCH;

    const size_t agElems = (size_t)BATCH * NM * NF;        // bf16: 67.1 MB
    unsigned short* Ag  = (unsigned short*)d_ws;
    unsigned short* W1p = Ag + agElems;
    unsigned short* W2p = W1p + NM*2048;
    unsigned short* W3p = W2p + NM*2048;
    float* scale1 = (float*)(W3p + NM*512);
    float* shift1 = scale1 + NM*L1;
    float* scale2 = shift1 + NM*L1;
    float* shift2 = scale2 + NM*L2O;
    float* arena  = shift2 + NM*L2O;
    const size_t prefixBytes = (char*)arena - (char*)d_ws;

    const size_t arenaA = (size_t)GS1B*8192*4*2;           // 16.8 MB
    const size_t needA = prefixBytes + arenaA;
    const size_t arenaB = (size_t)NM*L1*P64*4*2;           // 4.2 MB

    k_prep<<<NM*4608/256, 256, 0, stream>>>(W1, W2, W3, W1p, W2p, W3p);

    if (ws_size >= needA) {
        float* s1sum = arena;                       // [256][8192] slot-major
        float* s1sq  = s1sum + (size_t)GS1B*8192;
        float* s2sum = arena;                       // reuse after fin1
        float* s2sq  = s2sum + (size_t)NM*L2O*P64;
        float* outpartT = arena;                    // reuse after fin2

        k_gs1<<<GS1B, 512, 0, stream>>>(x, uf, W1p, Ag, s1sum, s1sq);
        k_fin<<<NM*L1/256, 256, 0, stream>>>(s1sum, s1sq, b1, g1, be1, scale1, shift1, NM*L1, GS1B, 1);
        k_stats2_p<<<NM*CH, 256, 0, stream>>>(Ag, W1p, scale1, shift1, W2p, s2sum, s2sq);
        k_fin<<<NM*L2O/256, 256, 0, stream>>>(s2sum, s2sq, b2, g2, be2, scale2, shift2, NM*L2O, P64, 0);
        k_final_p<<<NM*CH, 256, 0, stream>>>(Ag, W1p, scale1, shift1, W2p, scale2, shift2,
                                             W3p, b3, ow, pred, outpartT);
        k_outT<<<BATCH/256, 256, 0, stream>>>(outpartT, ob, out);
    } else {
        float* s1sum = arena;
        float* s1sq  = s1sum + (size_t)NM*L1*P64;
        float* outpartT = arena;                    // reuse after fin1
        float* s2sum = arena + arenaB/4;
        float* s2sq  = s2sum + (size_t)NM*L2O*P64;

        k_gather<<<BATCH/16, 256, 0, stream>>>(x, uf, Ag);
        k_stats1_m<<<NM*CH, 256, 0, stream>>>(Ag, W1p, s1sum, s1sq);
        k_fin<<<NM*L1/256, 256, 0, stream>>>(s1sum, s1sq, b1, g1, be1, scale1, shift1, NM*L1, P64, 0);
        k_stats2_p<<<NM*CH, 256, 0, stream>>>(Ag, W1p, scale1, shift1, W2p, s2sum, s2sq);
        k_fin<<<NM*L2O/256, 256, 0, stream>>>(s2sum, s2sq, b2, g2, be2, scale2, shift2, NM*L2O, P64, 0);
        k_final_p<<<NM*CH, 256, 0, stream>>>(Ag, W1p, scale1, shift1, W2p, scale2, shift2,
                                             W3p, b3, ow, pred, outpartT);
        k_outT<<<BATCH/256, 256, 0, stream>>>(outpartT, ob, out);
    }
}

// Round 13
// 113.895 us; speedup vs baseline: 1.7127x; 1.0042x over previous
//
#include <hip/hip_runtime.h>
#include <hip/hip_bf16.h>

#define BATCH   8192
#define NM      128      // n_models
#define NF      32       // n_feat
#define L1      64
#define L2O     32
#define L3O     16
#define INSZ    512
#define EPSV    1e-5f
#define CH      16       // chunks per model (stats2/final blocks)
#define P64     64       // partial slots, f-major layout (stats2 + path B)
#define GS1B    256      // k_gs1 blocks (path A), 32 rows each
#define XS_STR  522      // padded LDS stride (ushorts) for x image
#define H1STR   72       // h1 LDS row stride in shorts (144B: 16B-aligned, 2-way banks)
#define H2STR   40       // h2 LDS row stride in shorts (80B: 16B-aligned, 2-way banks)

typedef __attribute__((ext_vector_type(8))) short short8;
typedef __attribute__((ext_vector_type(4))) float f32x4;

union U8 { short8 s8; unsigned u[4]; };

__device__ inline unsigned short f2bf(float f) {
    union { float f; unsigned u; } v; v.f = f;
    return (unsigned short)((v.u + 0x7FFF + ((v.u >> 16) & 1)) >> 16);
}
__device__ inline unsigned pkbf(float a, float b) {
    union { __hip_bfloat162 h; unsigned u; } c;
    c.h = __float22bfloat162_rn(float2{a, b});
    return c.u;
}

// ---------- k_prep: pack W1/W2/W3 to bf16 fragment order ----------
__global__ __launch_bounds__(256) void k_prep(
    const float* __restrict__ W1, const float* __restrict__ W2,
    const float* __restrict__ W3,
    unsigned short* __restrict__ W1p, unsigned short* __restrict__ W2p,
    unsigned short* __restrict__ W3p)
{
    int g = blockIdx.x*256 + threadIdx.x;      // NM*4608 total
    int m = g / 4608, r = g % 4608;
    if (r < 2048) {
        int n = r >> 9, l = (r >> 3) & 63, s = r & 7;
        W1p[m*2048 + r] = f2bf(W1[m*2048 + ((l>>4)*8+s)*L1 + n*16 + (l&15)]);
    } else if (r < 4096) {
        int q = r - 2048;
        int f = q >> 9, l = (q >> 3) & 63, s = q & 7;
        int n2 = f >> 1, ks = f & 1;
        W2p[m*2048 + q] = f2bf(W2[m*2048 + (ks*32+(l>>4)*8+s)*L2O + n2*16 + (l&15)]);
    } else {
        int q = r - 4096;
        int l = (q >> 3) & 63, s = q & 7;
        W3p[m*512 + q] = f2bf(W3[m*512 + ((l>>4)*8+s)*L3O + (l&15)]);
    }
}

// ---------- k_gs1 (path A): fused gather + Ag write + stats1 partials ----------
__global__ __launch_bounds__(512) void k_gs1(
    const float* __restrict__ x, const int* __restrict__ uf,
    const unsigned short* __restrict__ W1p,
    unsigned short* __restrict__ Ag,
    float* __restrict__ s1sum, float* __restrict__ s1sq)
{
    __shared__ unsigned short xs[32*XS_STR];   // 33.4 KB
    __shared__ int sUf[NM*NF];                 // 16 KB
    const int blk = blockIdx.x, t = threadIdx.x;
    #pragma unroll
    for (int p = 0; p < 8; ++p) {
        const float4 v = *(const float4*)(x + (size_t)blk*32*INSZ + p*2048 + t*4);
        const int row = 4*p + (t>>7), col = (t&127)*4;
        *(unsigned*)(&xs[row*XS_STR + col])     = pkbf(v.x, v.y);
        *(unsigned*)(&xs[row*XS_STR + col + 2]) = pkbf(v.z, v.w);
    }
    #pragma unroll
    for (int p = 0; p < 2; ++p)
        ((int4*)sUf)[t + p*512] = ((const int4*)uf)[t + p*512];
    __syncthreads();

    const int w = t >> 6, l = t & 63, lr = l & 15, lg = l >> 4;
    const unsigned short* xr0 = xs + lr*XS_STR;
    const unsigned short* xr1 = xs + (16+lr)*XS_STR;
    for (int mi = 0; mi < 16; ++mi) {
        const int m = w*16 + mi;
        const int4 ia = ((const int4*)sUf)[m*8 + lg*2];
        const int4 ib = ((const int4*)sUf)[m*8 + lg*2 + 1];
        U8 A0, A1;
        A0.u[0] = xr0[ia.x] | ((unsigned)xr0[ia.y] << 16);
        A0.u[1] = xr0[ia.z] | ((unsigned)xr0[ia.w] << 16);
        A0.u[2] = xr0[ib.x] | ((unsigned)xr0[ib.y] << 16);
        A0.u[3] = xr0[ib.z] | ((unsigned)xr0[ib.w] << 16);
        A1.u[0] = xr1[ia.x] | ((unsigned)xr1[ia.y] << 16);
        A1.u[1] = xr1[ia.z] | ((unsigned)xr1[ia.w] << 16);
        A1.u[2] = xr1[ib.x] | ((unsigned)xr1[ib.y] << 16);
        A1.u[3] = xr1[ib.z] | ((unsigned)xr1[ib.w] << 16);
        *(short8*)(Ag + ((size_t)(blk*2  )*NM + m)*512 + lr*32 + lg*8) = A0.s8;
        *(short8*)(Ag + ((size_t)(blk*2+1)*NM + m)*512 + lr*32 + lg*8) = A1.s8;
        float sum[4], sq[4];
        #pragma unroll
        for (int n = 0; n < 4; ++n) {
            const short8 wf = *(const short8*)(W1p + m*2048 + n*512 + l*8);
            f32x4 z = {0.f,0.f,0.f,0.f};
            f32x4 c0 = __builtin_amdgcn_mfma_f32_16x16x32_bf16(A0.s8, wf, z, 0, 0, 0);
            f32x4 c1 = __builtin_amdgcn_mfma_f32_16x16x32_bf16(A1.s8, wf, z, 0, 0, 0);
            sum[n] = (c0[0]+c0[1]) + (c0[2]+c0[3]) + (c1[0]+c1[1]) + (c1[2]+c1[3]);
            sq[n]  = c0[0]*c0[0] + c0[1]*c0[1] + c0[2]*c0[2] + c0[3]*c0[3]
                   + c1[0]*c1[0] + c1[1]*c1[1] + c1[2]*c1[2] + c1[3]*c1[3];
        }
        #pragma unroll
        for (int n = 0; n < 4; ++n) {
            sum[n] += __shfl_xor(sum[n], 16); sum[n] += __shfl_xor(sum[n], 32);
            sq[n]  += __shfl_xor(sq[n], 16);  sq[n]  += __shfl_xor(sq[n], 32);
        }
        if (l < 16) {
            #pragma unroll
            for (int n = 0; n < 4; ++n) {
                s1sum[(size_t)blk*8192 + m*64 + n*16 + l] = sum[n];
                s1sq [(size_t)blk*8192 + m*64 + n*16 + l] = sq[n];
            }
        }
    }
}

// ---------- finalize (both layouts) ----------
__global__ __launch_bounds__(256) void k_fin(
    const float* __restrict__ sump, const float* __restrict__ sqp,
    const float* __restrict__ bias, const float* __restrict__ gamma,
    const float* __restrict__ beta, float* __restrict__ scale,
    float* __restrict__ shift, int nfeat, int parts, int slotMajor)
{
    int f = blockIdx.x*256 + threadIdx.x;
    if (f >= nfeat) return;
    float S = 0.f, Q = 0.f;
    if (slotMajor) {
        #pragma unroll 8
        for (int c = 0; c < parts; ++c) { S += sump[(size_t)c*nfeat + f]; Q += sqp[(size_t)c*nfeat + f]; }
    } else {
        #pragma unroll 8
        for (int c = 0; c < parts; ++c) { S += sump[(size_t)f*parts + c]; Q += sqp[(size_t)f*parts + c]; }
    }
    float mz   = S * (1.f/BATCH);
    float var  = Q * (1.f/BATCH) - mz*mz;     // shift-invariant
    float mean = mz + bias[f];
    float sc   = rsqrtf(var + EPSV) * gamma[f];
    scale[f] = sc; shift[f] = beta[f] - mean*sc;
}

// ---------- k_stats2_p: swapped-operand recompute with one-ahead Ag prefetch ----------
__global__ __launch_bounds__(256) void k_stats2_p(
    const unsigned short* __restrict__ Ag, const unsigned short* __restrict__ W1p,
    const float* __restrict__ scale1, const float* __restrict__ shift1,
    const unsigned short* __restrict__ W2p,
    float* __restrict__ sum2p, float* __restrict__ sq2p)
{
    __shared__ unsigned short h1T[4][16*H1STR];   // 9 KB
    const int m = blockIdx.x >> 4, chunk = blockIdx.x & 15;
    const int t = threadIdx.x, w = t >> 6, l = t & 63;
    const int lr = l & 15, lg = l >> 4;
    short8 w1f[4];
    #pragma unroll
    for (int n = 0; n < 4; ++n) w1f[n] = *(const short8*)(W1p + m*2048 + n*512 + l*8);
    short8 w2f[2][2];
    #pragma unroll
    for (int n2 = 0; n2 < 2; ++n2)
        #pragma unroll
        for (int ks = 0; ks < 2; ++ks)
            w2f[n2][ks] = *(const short8*)(W2p + m*2048 + (n2*2+ks)*512 + l*8);
    float4 sc1q[4], sh1q[4];
    #pragma unroll
    for (int n = 0; n < 4; ++n) {
        sc1q[n] = *(const float4*)(scale1 + m*L1 + n*16 + lg*4);
        sh1q[n] = *(const float4*)(shift1 + m*L1 + n*16 + lg*4);
    }
    unsigned short* hT = &h1T[w][0];
    const size_t fragOff = (size_t)lr*32 + lg*8;
    float sumf[8] = {0,0,0,0,0,0,0,0}, sqf[8] = {0,0,0,0,0,0,0,0};
    short8 aCur = *(const short8*)(Ag + ((size_t)(chunk*32 + w)*NM + m)*512 + fragOff);
    for (int i = 0; i < 8; ++i) {
        // issue next-iteration load BEFORE current compute (clamped; overlaps ~300cy of work)
        const int iN = (i < 7) ? i + 1 : 7;
        const short8 aNext = *(const short8*)(Ag + ((size_t)(chunk*32 + iN*4 + w)*NM + m)*512 + fragOff);
        #pragma unroll
        for (int n = 0; n < 4; ++n) {
            f32x4 z = {0.f,0.f,0.f,0.f};
            // swapped: lane holds z1^T rows = feats n*16+lg*4+r, col = batch lr
            f32x4 acc = __builtin_amdgcn_mfma_f32_16x16x32_bf16(w1f[n], aCur, z, 0, 0, 0);
            float h0 = acc[0]*sc1q[n].x + sh1q[n].x; h0 = h0 > 0.f ? h0 : 0.f;
            float h1 = acc[1]*sc1q[n].y + sh1q[n].y; h1 = h1 > 0.f ? h1 : 0.f;
            float h2 = acc[2]*sc1q[n].z + sh1q[n].z; h2 = h2 > 0.f ? h2 : 0.f;
            float h3 = acc[3]*sc1q[n].w + sh1q[n].w; h3 = h3 > 0.f ? h3 : 0.f;
            uint2 pk; pk.x = pkbf(h0, h1); pk.y = pkbf(h2, h3);
            *(uint2*)(hT + lr*H1STR + n*16 + lg*4) = pk;
        }
        const short8 a20 = *(const short8*)(hT + lr*H1STR + lg*8);
        const short8 a21 = *(const short8*)(hT + lr*H1STR + 32 + lg*8);
        #pragma unroll
        for (int n2 = 0; n2 < 2; ++n2) {
            f32x4 z = {0.f,0.f,0.f,0.f};
            f32x4 acc = __builtin_amdgcn_mfma_f32_16x16x32_bf16(w2f[n2][0], a20, z, 0, 0, 0);
            acc = __builtin_amdgcn_mfma_f32_16x16x32_bf16(w2f[n2][1], a21, acc, 0, 0, 0);
            #pragma unroll
            for (int r = 0; r < 4; ++r) {
                sumf[n2*4+r] += acc[r];
                sqf [n2*4+r] += acc[r]*acc[r];
            }
        }
        aCur = aNext;
    }
    #pragma unroll
    for (int j = 0; j < 8; ++j) {
        #pragma unroll
        for (int mk = 1; mk < 16; mk <<= 1) {
            sumf[j] += __shfl_xor(sumf[j], mk);
            sqf[j]  += __shfl_xor(sqf[j], mk);
        }
    }
    if (lr == 0) {
        const int slot = chunk*4 + w;
        #pragma unroll
        for (int n2 = 0; n2 < 2; ++n2)
            #pragma unroll
            for (int r = 0; r < 4; ++r) {
                const int f = m*L2O + n2*16 + lg*4 + r;
                sum2p[(size_t)f*P64 + slot] = sumf[n2*4+r];
                sq2p [(size_t)f*P64 + slot] = sqf[n2*4+r];
            }
    }
}

// ---------- k_final_p: swapped-operand full recompute with one-ahead Ag prefetch ----------
__global__ __launch_bounds__(256) void k_final_p(
    const unsigned short* __restrict__ Ag, const unsigned short* __restrict__ W1p,
    const float* __restrict__ scale1, const float* __restrict__ shift1,
    const unsigned short* __restrict__ W2p,
    const float* __restrict__ scale2, const float* __restrict__ shift2,
    const unsigned short* __restrict__ W3p, const float* __restrict__ b3,
    const float* __restrict__ ow,
    float* __restrict__ pred, float* __restrict__ outpartT)
{
    __shared__ unsigned short h1T[4][16*H1STR];   // 9 KB
    __shared__ unsigned short h2T[4][16*H2STR];   // 5 KB
    const int m = blockIdx.x >> 4, chunk = blockIdx.x & 15;
    const int t = threadIdx.x, w = t >> 6, l = t & 63;
    const int lr = l & 15, lg = l >> 4;
    short8 w1f[4];
    #pragma unroll
    for (int n = 0; n < 4; ++n) w1f[n] = *(const short8*)(W1p + m*2048 + n*512 + l*8);
    short8 w2f[2][2];
    #pragma unroll
    for (int n2 = 0; n2 < 2; ++n2)
        #pragma unroll
        for (int ks = 0; ks < 2; ++ks)
            w2f[n2][ks] = *(const short8*)(W2p + m*2048 + (n2*2+ks)*512 + l*8);
    const short8 w3f = *(const short8*)(W3p + m*512 + l*8);
    float4 sc1q[4], sh1q[4];
    #pragma unroll
    for (int n = 0; n < 4; ++n) {
        sc1q[n] = *(const float4*)(scale1 + m*L1 + n*16 + lg*4);
        sh1q[n] = *(const float4*)(shift1 + m*L1 + n*16 + lg*4);
    }
    float4 sc2q[2], sh2q[2];
    #pragma unroll
    for (int n2 = 0; n2 < 2; ++n2) {
        sc2q[n2] = *(const float4*)(scale2 + m*L2O + n2*16 + lg*4);
        sh2q[n2] = *(const float4*)(shift2 + m*L2O + n2*16 + lg*4);
    }
    const float4 b3f = *(const float4*)(b3 + m*L3O + lg*4);
    const float4 owf = *(const float4*)(ow + m*L3O + lg*4);
    f32x4 cb3; cb3[0] = b3f.x; cb3[1] = b3f.y; cb3[2] = b3f.z; cb3[3] = b3f.w;
    unsigned short* hT  = &h1T[w][0];
    unsigned short* hT2 = &h2T[w][0];
    const size_t fragOff = (size_t)lr*32 + lg*8;
    short8 aCur = *(const short8*)(Ag + ((size_t)(chunk*32 + w)*NM + m)*512 + fragOff);
    for (int i = 0; i < 8; ++i) {
        const int rbG = chunk*32 + i*4 + w;
        const int iN = (i < 7) ? i + 1 : 7;
        const short8 aNext = *(const short8*)(Ag + ((size_t)(chunk*32 + iN*4 + w)*NM + m)*512 + fragOff);
        #pragma unroll
        for (int n = 0; n < 4; ++n) {
            f32x4 z = {0.f,0.f,0.f,0.f};
            f32x4 acc = __builtin_amdgcn_mfma_f32_16x16x32_bf16(w1f[n], aCur, z, 0, 0, 0);
            float h0 = acc[0]*sc1q[n].x + sh1q[n].x; h0 = h0 > 0.f ? h0 : 0.f;
            float h1 = acc[1]*sc1q[n].y + sh1q[n].y; h1 = h1 > 0.f ? h1 : 0.f;
            float h2 = acc[2]*sc1q[n].z + sh1q[n].z; h2 = h2 > 0.f ? h2 : 0.f;
            float h3 = acc[3]*sc1q[n].w + sh1q[n].w; h3 = h3 > 0.f ? h3 : 0.f;
            uint2 pk; pk.x = pkbf(h0, h1); pk.y = pkbf(h2, h3);
            *(uint2*)(hT + lr*H1STR + n*16 + lg*4) = pk;
        }
        const short8 a20 = *(const short8*)(hT + lr*H1STR + lg*8);
        const short8 a21 = *(const short8*)(hT + lr*H1STR + 32 + lg*8);
        #pragma unroll
        for (int n2 = 0; n2 < 2; ++n2) {
            f32x4 z = {0.f,0.f,0.f,0.f};
            f32x4 acc = __builtin_amdgcn_mfma_f32_16x16x32_bf16(w2f[n2][0], a20, z, 0, 0, 0);
            acc = __builtin_amdgcn_mfma_f32_16x16x32_bf16(w2f[n2][1], a21, acc, 0, 0, 0);
            float h0 = acc[0]*sc2q[n2].x + sh2q[n2].x; h0 = h0 > 0.f ? h0 : 0.f;
            float h1 = acc[1]*sc2q[n2].y + sh2q[n2].y; h1 = h1 > 0.f ? h1 : 0.f;
            float h2 = acc[2]*sc2q[n2].z + sh2q[n2].z; h2 = h2 > 0.f ? h2 : 0.f;
            float h3 = acc[3]*sc2q[n2].w + sh2q[n2].w; h3 = h3 > 0.f ? h3 : 0.f;
            uint2 pk; pk.x = pkbf(h0, h1); pk.y = pkbf(h2, h3);
            *(uint2*)(hT2 + lr*H2STR + n2*16 + lg*4) = pk;
        }
        {
            const short8 a3 = *(const short8*)(hT2 + lr*H2STR + lg*8);
            // b3 folded into MFMA C operand (C layout == D layout, HW-verified r9/r10)
            f32x4 acc = __builtin_amdgcn_mfma_f32_16x16x32_bf16(w3f, a3, cb3, 0, 0, 0);
            float4 pv;
            pv.x = acc[0]; pv.y = acc[1]; pv.z = acc[2]; pv.w = acc[3];
            const size_t row = (size_t)rbG*16 + lr;
            *(float4*)(pred + row*(NM*L3O) + m*L3O + lg*4) = pv;
            float v = pv.x*owf.x + pv.y*owf.y + pv.z*owf.z + pv.w*owf.w;
            v += __shfl_xor(v, 16); v += __shfl_xor(v, 32);
            if (l < 16) outpartT[(size_t)m*BATCH + rbG*16 + l] = v;
        }
        aCur = aNext;
    }
}

// ---------- k_outT ----------
__global__ __launch_bounds__(256) void k_outT(
    const float* __restrict__ outpartT, const float* __restrict__ ob,
    float* __restrict__ out)
{
    int b = blockIdx.x*256 + threadIdx.x;
    float acc = ob[0];
    #pragma unroll 8
    for (int m = 0; m < NM; ++m) acc += outpartT[(size_t)m*BATCH + b];
    out[b] = acc;
}

// ---------- Path B fallback: separate gather + stats1 ----------
__global__ __launch_bounds__(256) void k_gather(
    const float* __restrict__ x, const int* __restrict__ uf,
    unsigned short* __restrict__ Ag)
{
    __shared__ float xs[16*INSZ];
    __shared__ int   sUf[NM*NF];
    const int rb = blockIdx.x;
    const int t  = threadIdx.x;
    const float4* xsrc = (const float4*)(x + (size_t)rb*16*INSZ);
    float4* xdst = (float4*)xs;
    #pragma unroll
    for (int p = 0; p < 8; ++p) xdst[t + p*256] = xsrc[t + p*256];
    const int4* us = (const int4*)uf;
    int4* ud = (int4*)sUf;
    #pragma unroll
    for (int p = 0; p < 4; ++p) ud[t + p*256] = us[t + p*256];
    __syncthreads();
    unsigned* outp = (unsigned*)(Ag + (size_t)rb*NM*512);
    const int e = t*2, r = e >> 5, j = e & 31;
    for (int m = 0; m < NM; ++m) {
        const int i0 = sUf[m*NF + j], i1 = sUf[m*NF + j + 1];
        outp[m*256 + t] = pkbf(xs[r*INSZ + i0], xs[r*INSZ + i1]);
    }
}

__global__ __launch_bounds__(256) void k_stats1_m(
    const unsigned short* __restrict__ Ag, const unsigned short* __restrict__ W1p,
    float* __restrict__ sum1p, float* __restrict__ sq1p)
{
    const int m = blockIdx.x >> 4, chunk = blockIdx.x & 15;
    const int t = threadIdx.x, w = t >> 6, l = t & 63;
    const int lr = l & 15, lg = l >> 4;
    short8 w1f[4];
    #pragma unroll
    for (int n = 0; n < 4; ++n) w1f[n] = *(const short8*)(W1p + m*2048 + n*512 + l*8);
    float sum[4] = {0,0,0,0}, sq[4] = {0,0,0,0};
    for (int i = 0; i < 8; ++i) {
        const int rbG = chunk*32 + i*4 + w;
        const short8 a = *(const short8*)(Ag + ((size_t)rbG*NM + m)*512 + lr*32 + lg*8);
        #pragma unroll
        for (int n = 0; n < 4; ++n) {
            f32x4 acc = {0.f,0.f,0.f,0.f};
            acc = __builtin_amdgcn_mfma_f32_16x16x32_bf16(a, w1f[n], acc, 0, 0, 0);
            sum[n] += (acc[0]+acc[1]) + (acc[2]+acc[3]);
            sq[n]  += acc[0]*acc[0] + acc[1]*acc[1] + acc[2]*acc[2] + acc[3]*acc[3];
        }
    }
    #pragma unroll
    for (int n = 0; n < 4; ++n) {
        sum[n] += __shfl_xor(sum[n], 16); sum[n] += __shfl_xor(sum[n], 32);
        sq[n]  += __shfl_xor(sq[n], 16);  sq[n]  += __shfl_xor(sq[n], 32);
    }
    if (l < 16) {
        const int slot = chunk*4 + w;
        #pragma unroll
        for (int n = 0; n < 4; ++n) {
            const int f = m*L1 + n*16 + l;
            sum1p[(size_t)f*P64 + slot] = sum[n];
            sq1p [(size_t)f*P64 + slot] = sq[n];
        }
    }
}

extern "C" void kernel_launch(void* const* d_in, const int* in_sizes, int n_in,
                              void* d_out, int out_size, void* d_ws, size_t ws_size,
                              hipStream_t stream) {
    const float* x   = (const float*)d_in[0];
    const int*   uf  = (const int*  )d_in[1];
    const float* W1  = (const float*)d_in[2];
    const float* b1  = (const float*)d_in[3];
    const float* W2  = (const float*)d_in[4];
    const float* b2  = (const float*)d_in[5];
    const float* W3  = (const float*)d_in[6];
    const float* b3  = (const float*)d_in[7];
    const float* g1  = (const float*)d_in[8];
    const float* be1 = (const float*)d_in[9];
    const float* g2  = (const float*)d_in[10];
    const float* be2 = (const float*)d_in[11];
    const float* ow  = (const float*)d_in[12];
    const float* ob  = (const float*)d_in[13];

    float* out  = (float*)d_out;
    float* pred = out + BATCH;

    const size_t agElems = (size_t)BATCH * NM * NF;        // bf16: 67.1 MB
    unsigned short* Ag  = (unsigned short*)d_ws;
    unsigned short* W1p = Ag + agElems;
    unsigned short* W2p = W1p + NM*2048;
    unsigned short* W3p = W2p + NM*2048;
    float* scale1 = (float*)(W3p + NM*512);
    float* shift1 = scale1 + NM*L1;
    float* scale2 = shift1 + NM*L1;
    float* shift2 = scale2 + NM*L2O;
    float* arena  = shift2 + NM*L2O;
    const size_t prefixBytes = (char*)arena - (char*)d_ws;

    const size_t arenaA = (size_t)GS1B*8192*4*2;           // 16.8 MB
    const size_t needA = prefixBytes + arenaA;
    const size_t arenaB = (size_t)NM*L1*P64*4*2;           // 4.2 MB

    k_prep<<<NM*4608/256, 256, 0, stream>>>(W1, W2, W3, W1p, W2p, W3p);

    if (ws_size >= needA) {
        float* s1sum = arena;                       // [256][8192] slot-major
        float* s1sq  = s1sum + (size_t)GS1B*8192;
        float* s2sum = arena;                       // reuse after fin1
        float* s2sq  = s2sum + (size_t)NM*L2O*P64;
        float* outpartT = arena;                    // reuse after fin2

        k_gs1<<<GS1B, 512, 0, stream>>>(x, uf, W1p, Ag, s1sum, s1sq);
        k_fin<<<NM*L1/256, 256, 0, stream>>>(s1sum, s1sq, b1, g1, be1, scale1, shift1, NM*L1, GS1B, 1);
        k_stats2_p<<<NM*CH, 256, 0, stream>>>(Ag, W1p, scale1, shift1, W2p, s2sum, s2sq);
        k_fin<<<NM*L2O/256, 256, 0, stream>>>(s2sum, s2sq, b2, g2, be2, scale2, shift2, NM*L2O, P64, 0);
        k_final_p<<<NM*CH, 256, 0, stream>>>(Ag, W1p, scale1, shift1, W2p, scale2, shift2,
                                             W3p, b3, ow, pred, outpartT);
        k_outT<<<BATCH/256, 256, 0, stream>>>(outpartT, ob, out);
    } else {
        float* s1sum = arena;
        float* s1sq  = s1sum + (size_t)NM*L1*P64;
        float* outpartT = arena;                    // reuse after fin1
        float* s2sum = arena + arenaB/4;
        float* s2sq  = s2sum + (size_t)NM*L2O*P64;

        k_gather<<<BATCH/16, 256, 0, stream>>>(x, uf, Ag);
        k_stats1_m<<<NM*CH, 256, 0, stream>>>(Ag, W1p, s1sum, s1sq);
        k_fin<<<NM*L1/256, 256, 0, stream>>>(s1sum, s1sq, b1, g1, be1, scale1, shift1, NM*L1, P64, 0);
        k_stats2_p<<<NM*CH, 256, 0, stream>>>(Ag, W1p, scale1, shift1, W2p, s2sum, s2sq);
        k_fin<<<NM*L2O/256, 256, 0, stream>>>(s2sum, s2sq, b2, g2, be2, scale2, shift2, NM*L2O, P64, 0);
        k_final_p<<<NM*CH, 256, 0, stream>>>(Ag, W1p, scale1, shift1, W2p, scale2, shift2,
                                             W3p, b3, ow, pred, outpartT);
        k_outT<<<BATCH/256, 256, 0, stream>>>(outpartT, ob, out);
    }
}